// Round 9
// baseline (998.370 us; speedup 1.0000x reference)
//
#include <hip/hip_runtime.h>
#include <math.h>

#define BB 64
#define SS 256
#define D_IN 400
#define D_RNN 200
#define HID 256
#define G4 1024   // 4*HID

// workspace layout (float offsets)
#define OFF_WTLIN 0                            // [400][200] f32
#define OFF_WTIH  (OFF_WTLIN + 400*200)        // [2][100][1024] u32 (f16 pairs)
#define OFF_WPACK (OFF_WTIH + 2*200*1024)      // [2][8 chunk][16 j][64 rg][4 ks] uint4
#define OFF_X     (OFF_WPACK + 2*1024*256/2)   // [2][64][256][200] f32
#define OFF_GX    (OFF_X + 2*64*256*200)       // [2][64][256][1024] f32

typedef _Float16 half2_t __attribute__((ext_vector_type(2)));

__device__ __forceinline__ half2_t u2h(unsigned u) {
    union { unsigned u; half2_t h; } x; x.u = u; return x.h;
}

__device__ __forceinline__ float dot2acc(unsigned hu, unsigned wu, float acc) {
#if __has_builtin(__builtin_amdgcn_fdot2)
    return __builtin_amdgcn_fdot2(u2h(hu), u2h(wu), acc, false);
#else
    half2_t h = u2h(hu), w = u2h(wu);
    acc = fmaf((float)h.x, (float)w.x, acc);
    acc = fmaf((float)h.y, (float)w.y, acc);
    return acc;
#endif
}

__device__ __forceinline__ unsigned packf16(float a, float b) {
    union { _Float16 h[2]; unsigned u; } x;
    x.h[0] = (_Float16)a; x.h[1] = (_Float16)b;
    return x.u;
}

__device__ __forceinline__ float sigm_f(float x) {
    return 1.0f / (1.0f + __expf(-x));
}
__device__ __forceinline__ float tanh_f(float x) {
    return 2.0f / (1.0f + __expf(-2.0f * x)) - 1.0f;
}

// quad (4-lane) butterfly sum via DPP: quad = {4rg+0..4rg+3} holds ks 0..3
__device__ __forceinline__ float quad_sum(float v) {
    int i = __float_as_int(v);
    v += __int_as_float(__builtin_amdgcn_update_dpp(0, i, 0xB1, 0xF, 0xF, true));
    i = __float_as_int(v);
    v += __int_as_float(__builtin_amdgcn_update_dpp(0, i, 0x4E, 0xF, 0xF, true));
    return v;
}

// ---------------- transposes / packs ----------------
__global__ void kt_wlin(const float* __restrict__ W, float* __restrict__ Wt) {
    int id = blockIdx.x * 256 + threadIdx.x;
    if (id >= D_RNN * D_IN) return;
    int j = id / D_IN, k = id % D_IN;
    Wt[k * D_RNN + j] = W[id];
}

// Wih f32 [1024][200] -> f16-pair pack
__global__ void kt_wih16(const float* __restrict__ Wl, const float* __restrict__ Wr,
                         unsigned* __restrict__ Wt16) {
    int id = blockIdx.x * 256 + threadIdx.x;
    if (id >= 2 * G4 * 100) return;
    int dir = id / (G4 * 100);
    int rem = id % (G4 * 100);
    int j = rem / 100, kk = rem % 100;
    const float* src = dir ? Wr : Wl;
    Wt16[(dir * 100 + kk) * G4 + j] = packf16(src[j * D_RNN + 2 * kk],
                                              src[j * D_RNN + 2 * kk + 1]);
}

// Whh f32 [1024][256] -> wp4[dir][i<8][j<16][rg<64][ks<4] uint4 of 8 f16,
// covering gate-row (j*64+rg), k in [ks*64 + i*8, +8). Lane-consecutive in (rg,ks).
__global__ void kt_wpack4(const float* __restrict__ Wl, const float* __restrict__ Wr,
                          uint4* __restrict__ Wp) {
    int id = blockIdx.x * 256 + threadIdx.x;     // uint4 id, total 65536
    if (id >= 2 * 8 * 16 * 256) return;
    int dir = id >> 15;
    int r = id & 32767;
    int ij = r >> 8;                // i*16 + j
    int i = ij >> 4, j = ij & 15;
    int t = r & 255;
    int rg = t >> 2, ks = t & 3;
    int row = j * 64 + rg;
    int k0 = ks * 64 + i * 8;
    const float* src = dir ? Wr : Wl;
    union { unsigned short h[8]; uint4 u; } o;
    #pragma unroll
    for (int q = 0; q < 8; q++)
        o.h[q] = __builtin_bit_cast(unsigned short, (_Float16)src[row * HID + k0 + q]);
    Wp[id] = o.u;
}

// ---------------- K1: embeddings + concat + linear + tanh ----------------
__launch_bounds__(512)
__global__ void k_embed_linear(const int* __restrict__ ci, const int* __restrict__ bli,
                               const int* __restrict__ bri, const int* __restrict__ sci,
                               const int* __restrict__ sbli, const int* __restrict__ sbri,
                               const float* __restrict__ ce, const float* __restrict__ be,
                               const float* __restrict__ sce, const float* __restrict__ sbe,
                               const float* __restrict__ Wt, const float* __restrict__ blin,
                               float* __restrict__ xout) {
    __shared__ __align__(16) float vec[16][2][D_IN];
    __shared__ int idx[16][6];
    int tid = threadIdx.x;
    int g0 = blockIdx.x * 16;

    if (tid < 96) {
        int tt = tid / 6, w = tid % 6;
        int g = g0 + tt;
        const int* arr = (w == 0) ? ci : (w == 1) ? sci : (w == 2) ? bli
                         : (w == 3) ? bri : (w == 4) ? sbli : sbri;
        idx[tt][w] = arr[g];
    }
    __syncthreads();

    for (int v = tid; v < 16 * D_IN; v += 512) {
        int tt = v / D_IN, p = v % D_IN;
        float lv, rv;
        if (p < 100)      { float e = ce[idx[tt][0] * 100 + p];          lv = rv = e; }
        else if (p < 200) { float e = sce[idx[tt][1] * 100 + (p - 100)]; lv = rv = e; }
        else if (p < 300) { int q = p - 200;
                            lv = be[idx[tt][2] * 100 + q];
                            rv = be[idx[tt][3] * 100 + q]; }
        else              { int q = p - 300;
                            lv = sbe[idx[tt][4] * 100 + q];
                            rv = sbe[idx[tt][5] * 100 + q]; }
        vec[tt][0][p] = lv;
        vec[tt][1][p] = rv;
    }
    __syncthreads();

    if (tid < 400) {
        int side = tid / 200, j = tid % 200;
        float acc[16];
        #pragma unroll
        for (int t = 0; t < 16; t++) acc[t] = 0.0f;

        for (int k4 = 0; k4 < D_IN / 4; k4++) {
            float w0 = Wt[(4 * k4 + 0) * D_RNN + j];
            float w1 = Wt[(4 * k4 + 1) * D_RNN + j];
            float w2 = Wt[(4 * k4 + 2) * D_RNN + j];
            float w3 = Wt[(4 * k4 + 3) * D_RNN + j];
            #pragma unroll
            for (int t = 0; t < 16; t++) {
                float4 xv = *(const float4*)&vec[t][side][4 * k4];
                acc[t] += xv.x * w0 + xv.y * w1 + xv.z * w2 + xv.w * w3;
            }
        }
        float bias = blin[j];
        #pragma unroll
        for (int t = 0; t < 16; t++) {
            int g = g0 + t;
            int b = g >> 8, s = g & 255;
            xout[((side * BB + b) * SS + s) * D_RNN + j] = tanh_f(acc[t] + bias);
        }
    }
}

// ---------------- K2: gate-x GEMM via f16 dot2 ----------------
__launch_bounds__(512)
__global__ void k_gatex(const float* __restrict__ x, const unsigned* __restrict__ Wt16,
                        const float* __restrict__ bihl, const float* __restrict__ bhhl,
                        const float* __restrict__ bihr, const float* __restrict__ bhhr,
                        float* __restrict__ gx) {
    __shared__ __align__(16) unsigned xT16[100][40];
    int tid = threadIdx.x;
    int id = blockIdx.x;
    int dir = id >> 9;
    int rem = id & 511;
    int b = rem >> 3;
    int s0 = (rem & 7) * 32;

    const float2* xb2 = reinterpret_cast<const float2*>(
        x + ((dir * BB + b) * SS + s0) * D_RNN);
    for (int v = tid; v < 32 * 100; v += 512) {
        int tok = v / 100, kk = v % 100;
        float2 p = xb2[tok * 100 + kk];
        xT16[kk][tok] = packf16(p.x, p.y);
    }
    __syncthreads();

    const unsigned* Wp = Wt16 + dir * 100 * G4;
    int j0 = tid, j1 = tid + 512;
    float acc0[32], acc1[32];
    #pragma unroll
    for (int t = 0; t < 32; t++) { acc0[t] = 0.0f; acc1[t] = 0.0f; }

    for (int kk = 0; kk < 100; kk++) {
        unsigned w0 = Wp[kk * G4 + j0];
        unsigned w1 = Wp[kk * G4 + j1];
        #pragma unroll
        for (int m = 0; m < 8; m++) {
            uint4 xx = *(const uint4*)&xT16[kk][4 * m];
            acc0[4 * m + 0] = dot2acc(xx.x, w0, acc0[4 * m + 0]);
            acc0[4 * m + 1] = dot2acc(xx.y, w0, acc0[4 * m + 1]);
            acc0[4 * m + 2] = dot2acc(xx.z, w0, acc0[4 * m + 2]);
            acc0[4 * m + 3] = dot2acc(xx.w, w0, acc0[4 * m + 3]);
            acc1[4 * m + 0] = dot2acc(xx.x, w1, acc1[4 * m + 0]);
            acc1[4 * m + 1] = dot2acc(xx.y, w1, acc1[4 * m + 1]);
            acc1[4 * m + 2] = dot2acc(xx.z, w1, acc1[4 * m + 2]);
            acc1[4 * m + 3] = dot2acc(xx.w, w1, acc1[4 * m + 3]);
        }
    }

    float bs0, bs1;
    if (dir) { bs0 = bihr[j0] + bhhr[j0]; bs1 = bihr[j1] + bhhr[j1]; }
    else     { bs0 = bihl[j0] + bhhl[j0]; bs1 = bihl[j1] + bhhl[j1]; }

    float* gbase = gx + ((dir * BB + b) * SS + s0) * G4;
    #pragma unroll
    for (int t = 0; t < 32; t++) {
        gbase[t * G4 + j0] = acc0[t] + bs0;
        gbase[t * G4 + j1] = acc1[t] + bs1;
    }
}

// ---------------- K3: LSTM, ONE block per (dir,b). 256 thr, 1 wave/SIMD.
// Thread (rg=t>>2, ks=t&3) owns 16 gate rows {j*64+rg} over k in [ks*64,+64).
// Weight chunks (uint4 = 8 k): i0-3 AGPR (256), i4-5 + i6-even VGPR (160),
// i6-odd + i7 from LDS (padded rows, bank-even). Cross-ks reduce = DPP quad.
// Thread t finalizes h-column t. Two barriers/step, zero cross-CU traffic.
__global__ void
__attribute__((amdgpu_flat_work_group_size(256, 256), amdgpu_waves_per_eu(1, 1)))
k_lstm(const uint4* __restrict__ wp4, const float* __restrict__ gx,
       float* __restrict__ out) {
    __shared__ __align__(16) uint4 wl7[1024 * 5];     // 80 KB, [(j*64+rg)*5 + ks]
    __shared__ __align__(16) uint4 wl6[512 * 5];      // 40 KB, [((j>>1)*64+rg)*5 + ks]
    __shared__ __align__(16) float4 gates4[256];      // 4 KB, [col] = {g0,g1,g2,g3}
    __shared__ __align__(16) unsigned hbuf[128];      // 512 B, h[ks][64k] as f16 pairs

    int t = threadIdx.x;
    int rg = t >> 2, ks = t & 3;
    int bid = blockIdx.x;
    int dir = bid >> 6, b = bid & 63;

    const uint4* wp = wp4 + (size_t)dir * 32768;

    // ---- one-time weight loads (fully coalesced: idx = (i*16+j)*256 + t) ----
    uint4 wa[4][16];
    #pragma unroll
    for (int i = 0; i < 4; i++)
        #pragma unroll
        for (int j = 0; j < 16; j++)
            wa[i][j] = wp[((i * 16 + j) << 8) + t];
    #pragma unroll
    for (int i = 0; i < 4; i++)
        #pragma unroll
        for (int j = 0; j < 16; j++)
            asm volatile("" : "+a"(wa[i][j].x), "+a"(wa[i][j].y),
                              "+a"(wa[i][j].z), "+a"(wa[i][j].w));

    uint4 wv[2][16];
    #pragma unroll
    for (int i = 0; i < 2; i++)
        #pragma unroll
        for (int j = 0; j < 16; j++)
            wv[i][j] = wp[(((i + 4) * 16 + j) << 8) + t];
    uint4 wv6[8];
    #pragma unroll
    for (int jj = 0; jj < 8; jj++)
        wv6[jj] = wp[((6 * 16 + 2 * jj) << 8) + t];
    #pragma unroll
    for (int i = 0; i < 2; i++)
        #pragma unroll
        for (int j = 0; j < 16; j++)
            asm volatile("" : "+v"(wv[i][j].x), "+v"(wv[i][j].y),
                              "+v"(wv[i][j].z), "+v"(wv[i][j].w));
    #pragma unroll
    for (int jj = 0; jj < 8; jj++)
        asm volatile("" : "+v"(wv6[jj].x), "+v"(wv6[jj].y),
                          "+v"(wv6[jj].z), "+v"(wv6[jj].w));

    // stage chunk6-odd and chunk7 into LDS (padded row stride 5 -> bank-even)
    int lbase = rg * 5 + ks;
    #pragma unroll
    for (int jj = 0; jj < 8; jj++)
        wl6[jj * 320 + lbase] = wp[((6 * 16 + 2 * jj + 1) << 8) + t];
    #pragma unroll
    for (int j = 0; j < 16; j++)
        wl7[j * 320 + lbase] = wp[((7 * 16 + j) << 8) + t];

    if (t < 128) hbuf[t] = 0u;

    const float* gxp = gx + (size_t)(dir * BB + b) * SS * G4;
    float* outp = out + (size_t)b * SS * (2 * HID) + dir * HID + t;
    float cst = 0.0f;
    int ts = dir ? (SS - 1) : 0;
    int dstep = dir ? -1 : 1;
    float gxc[4];
    #pragma unroll
    for (int g = 0; g < 4; g++) gxc[g] = gxp[(size_t)ts * G4 + g * 256 + t];
    __syncthreads();

    int hbase = ks * 32;
    float* gflat = reinterpret_cast<float*>(gates4);
    unsigned short* hs = reinterpret_cast<unsigned short*>(hbuf);

    for (int s = 0; s < SS; s++) {
        // ---- h slice: 8 uint4, wave-uniform per ks (LDS broadcast) ----
        uint4 h0 = *(const uint4*)&hbuf[hbase + 0];
        uint4 h1 = *(const uint4*)&hbuf[hbase + 4];
        uint4 h2 = *(const uint4*)&hbuf[hbase + 8];
        uint4 h3 = *(const uint4*)&hbuf[hbase + 12];
        uint4 h4 = *(const uint4*)&hbuf[hbase + 16];
        uint4 h5 = *(const uint4*)&hbuf[hbase + 20];
        uint4 h6 = *(const uint4*)&hbuf[hbase + 24];
        uint4 h7 = *(const uint4*)&hbuf[hbase + 28];

        float acc[16];
        #pragma unroll
        for (int j = 0; j < 16; j++) acc[j] = 0.0f;

#define DOT4(A, H, W4) \
        A = dot2acc((H).x, (W4).x, A); A = dot2acc((H).y, (W4).y, A); \
        A = dot2acc((H).z, (W4).z, A); A = dot2acc((H).w, (W4).w, A);

        #pragma unroll
        for (int j = 0; j < 16; j++) { DOT4(acc[j], h0, wa[0][j]); }
        #pragma unroll
        for (int j = 0; j < 16; j++) { DOT4(acc[j], h1, wa[1][j]); }
        #pragma unroll
        for (int j = 0; j < 16; j++) { DOT4(acc[j], h2, wa[2][j]); }
        #pragma unroll
        for (int j = 0; j < 16; j++) { DOT4(acc[j], h3, wa[3][j]); }
        #pragma unroll
        for (int j = 0; j < 16; j++) { DOT4(acc[j], h4, wv[0][j]); }
        #pragma unroll
        for (int j = 0; j < 16; j++) { DOT4(acc[j], h5, wv[1][j]); }
        // chunk 6: even j from regs, odd j from LDS
        #pragma unroll
        for (int jj = 0; jj < 8; jj++) { DOT4(acc[2 * jj], h6, wv6[jj]); }
        #pragma unroll
        for (int jj = 0; jj < 8; jj++) {
            uint4 w6 = wl6[jj * 320 + lbase];
            DOT4(acc[2 * jj + 1], h6, w6);
        }
        // chunk 7 from LDS
        #pragma unroll
        for (int j = 0; j < 16; j++) {
            uint4 w7 = wl7[j * 320 + lbase];
            DOT4(acc[j], h7, w7);
        }
#undef DOT4

        // ---- cross-ks reduction (DPP quad butterfly) ----
        #pragma unroll
        for (int j = 0; j < 16; j++) acc[j] = quad_sum(acc[j]);

        if (ks == 0) {
            #pragma unroll
            for (int j = 0; j < 16; j++) {
                int col = (j & 3) * 64 + rg;
                gflat[col * 4 + (j >> 2)] = acc[j];
            }
        }
        __syncthreads();

        // ---- finalize column t ----
        {
            float4 gt = gates4[t];
            float ig = sigm_f(gt.x + gxc[0]);
            float fg = sigm_f(gt.y + gxc[1]);
            float gg = tanh_f(gt.z + gxc[2]);
            float og = sigm_f(gt.w + gxc[3]);
            cst = fg * cst + ig * gg;
            float hv = og * tanh_f(cst);
            outp[(size_t)ts * (2 * HID)] = hv;
            hs[t] = __builtin_bit_cast(unsigned short, (_Float16)hv);
            // prefetch next step's gx (covered by barrier + next dots)
            int tn = (s < SS - 1) ? (ts + dstep) : ts;
            #pragma unroll
            for (int g = 0; g < 4; g++) gxc[g] = gxp[(size_t)tn * G4 + g * 256 + t];
        }
        __syncthreads();

        ts += dstep;
    }
}

extern "C" void kernel_launch(void* const* d_in, const int* in_sizes, int n_in,
                              void* d_out, int out_size, void* d_ws, size_t ws_size,
                              hipStream_t stream) {
    const int* char_features      = (const int*)d_in[0];
    const int* bichar_left        = (const int*)d_in[1];
    const int* bichar_right       = (const int*)d_in[2];
    const int* static_char        = (const int*)d_in[3];
    const int* static_bichar_left = (const int*)d_in[4];
    const int* static_bichar_right= (const int*)d_in[5];
    const float* char_emb         = (const float*)d_in[6];
    const float* bichar_emb       = (const float*)d_in[7];
    const float* static_char_emb  = (const float*)d_in[8];
    const float* static_bichar_emb= (const float*)d_in[9];
    const float* W_lin            = (const float*)d_in[10];
    const float* b_lin            = (const float*)d_in[11];
    const float* Wih_l            = (const float*)d_in[12];
    const float* Whh_l            = (const float*)d_in[13];
    const float* bih_l            = (const float*)d_in[14];
    const float* bhh_l            = (const float*)d_in[15];
    const float* Wih_r            = (const float*)d_in[16];
    const float* Whh_r            = (const float*)d_in[17];
    const float* bih_r            = (const float*)d_in[18];
    const float* bhh_r            = (const float*)d_in[19];

    float* ws    = (float*)d_ws;
    float* wtlin = ws + OFF_WTLIN;
    unsigned* wtih16 = (unsigned*)(ws + OFF_WTIH);
    uint4* wp4   = (uint4*)(ws + OFF_WPACK);
    float* xbuf  = ws + OFF_X;
    float* gxbuf = ws + OFF_GX;
    float* out   = (float*)d_out;

    kt_wlin<<<(D_RNN * D_IN + 255) / 256, 256, 0, stream>>>(W_lin, wtlin);
    kt_wih16<<<(2 * G4 * 100 + 255) / 256, 256, 0, stream>>>(Wih_l, Wih_r, wtih16);
    kt_wpack4<<<(2 * 8 * 16 * 256) / 256, 256, 0, stream>>>(Whh_l, Whh_r, wp4);

    k_embed_linear<<<(BB * SS) / 16, 512, 0, stream>>>(
        char_features, bichar_left, bichar_right, static_char,
        static_bichar_left, static_bichar_right,
        char_emb, bichar_emb, static_char_emb, static_bichar_emb,
        wtlin, b_lin, xbuf);

    k_gatex<<<(2 * BB * SS) / 32, 512, 0, stream>>>(
        xbuf, wtih16, bih_l, bhh_l, bih_r, bhh_r, gxbuf);

    k_lstm<<<2 * BB, 256, 0, stream>>>(wp4, gxbuf, out);
}

// Round 10
// 899.034 us; speedup vs baseline: 1.1105x; 1.1105x over previous
//
#include <hip/hip_runtime.h>
#include <math.h>

#define BB 64
#define SS 256
#define D_IN 400
#define D_RNN 200
#define HID 256
#define G4 1024   // 4*HID

// workspace layout (float offsets)
#define OFF_WTLIN 0                            // [400][200] f32
#define OFF_WTIH  (OFF_WTLIN + 400*200)        // [2][100][1024] u32 (f16 pairs)
#define OFF_WPACK (OFF_WTIH + 2*200*1024)      // [2][128 chunk][256 thr] uint4
#define OFF_X     (OFF_WPACK + 2*1024*256/2)   // [2][64][256][200] f32
#define OFF_GX    (OFF_X + 2*64*256*200)       // [2][64][256][1024] f32

typedef _Float16 half2_t __attribute__((ext_vector_type(2)));

__device__ __forceinline__ half2_t u2h(unsigned u) {
    union { unsigned u; half2_t h; } x; x.u = u; return x.h;
}

__device__ __forceinline__ float dot2acc(unsigned hu, unsigned wu, float acc) {
#if __has_builtin(__builtin_amdgcn_fdot2)
    return __builtin_amdgcn_fdot2(u2h(hu), u2h(wu), acc, false);
#else
    half2_t h = u2h(hu), w = u2h(wu);
    acc = fmaf((float)h.x, (float)w.x, acc);
    acc = fmaf((float)h.y, (float)w.y, acc);
    return acc;
#endif
}

__device__ __forceinline__ unsigned packf16(float a, float b) {
    union { _Float16 h[2]; unsigned u; } x;
    x.h[0] = (_Float16)a; x.h[1] = (_Float16)b;
    return x.u;
}

__device__ __forceinline__ float sigm_f(float x) {
    return 1.0f / (1.0f + __expf(-x));
}
__device__ __forceinline__ float tanh_f(float x) {
    return 2.0f / (1.0f + __expf(-2.0f * x)) - 1.0f;
}

// quad (4-lane) butterfly sum via DPP: quad = {4rg+0..4rg+3} holds ks 0..3
__device__ __forceinline__ float quad_sum(float v) {
    int i = __float_as_int(v);
    v += __int_as_float(__builtin_amdgcn_update_dpp(0, i, 0xB1, 0xF, 0xF, true));
    i = __float_as_int(v);
    v += __int_as_float(__builtin_amdgcn_update_dpp(0, i, 0x4E, 0xF, 0xF, true));
    return v;
}

// ---------------- transposes / packs ----------------
__global__ void kt_wlin(const float* __restrict__ W, float* __restrict__ Wt) {
    int id = blockIdx.x * 256 + threadIdx.x;
    if (id >= D_RNN * D_IN) return;
    int j = id / D_IN, k = id % D_IN;
    Wt[k * D_RNN + j] = W[id];
}

// Wih f32 [1024][200] -> f16-pair pack
__global__ void kt_wih16(const float* __restrict__ Wl, const float* __restrict__ Wr,
                         unsigned* __restrict__ Wt16) {
    int id = blockIdx.x * 256 + threadIdx.x;
    if (id >= 2 * G4 * 100) return;
    int dir = id / (G4 * 100);
    int rem = id % (G4 * 100);
    int j = rem / 100, kk = rem % 100;
    const float* src = dir ? Wr : Wl;
    Wt16[(dir * 100 + kk) * G4 + j] = packf16(src[j * D_RNN + 2 * kk],
                                              src[j * D_RNN + 2 * kk + 1]);
}

// Whh f32 [1024][256] -> wp[dir][q=(i*16+j)][t=(rg*4+ks)] uint4 of 8 f16:
// gate-row (j*64+rg), k in [ks*64 + i*8, +8).
__global__ void kt_wpack4(const float* __restrict__ Wl, const float* __restrict__ Wr,
                          uint4* __restrict__ Wp) {
    int id = blockIdx.x * 256 + threadIdx.x;     // uint4 id, total 65536
    if (id >= 2 * 8 * 16 * 256) return;
    int dir = id >> 15;
    int r = id & 32767;
    int ij = r >> 8;                // i*16 + j
    int i = ij >> 4, j = ij & 15;
    int t = r & 255;
    int rg = t >> 2, ks = t & 3;
    int row = j * 64 + rg;
    int k0 = ks * 64 + i * 8;
    const float* src = dir ? Wr : Wl;
    union { unsigned short h[8]; uint4 u; } o;
    #pragma unroll
    for (int q = 0; q < 8; q++)
        o.h[q] = __builtin_bit_cast(unsigned short, (_Float16)src[row * HID + k0 + q]);
    Wp[id] = o.u;
}

// ---------------- K1: embeddings + concat + linear + tanh ----------------
__launch_bounds__(512)
__global__ void k_embed_linear(const int* __restrict__ ci, const int* __restrict__ bli,
                               const int* __restrict__ bri, const int* __restrict__ sci,
                               const int* __restrict__ sbli, const int* __restrict__ sbri,
                               const float* __restrict__ ce, const float* __restrict__ be,
                               const float* __restrict__ sce, const float* __restrict__ sbe,
                               const float* __restrict__ Wt, const float* __restrict__ blin,
                               float* __restrict__ xout) {
    __shared__ __align__(16) float vec[16][2][D_IN];
    __shared__ int idx[16][6];
    int tid = threadIdx.x;
    int g0 = blockIdx.x * 16;

    if (tid < 96) {
        int tt = tid / 6, w = tid % 6;
        int g = g0 + tt;
        const int* arr = (w == 0) ? ci : (w == 1) ? sci : (w == 2) ? bli
                         : (w == 3) ? bri : (w == 4) ? sbli : sbri;
        idx[tt][w] = arr[g];
    }
    __syncthreads();

    for (int v = tid; v < 16 * D_IN; v += 512) {
        int tt = v / D_IN, p = v % D_IN;
        float lv, rv;
        if (p < 100)      { float e = ce[idx[tt][0] * 100 + p];          lv = rv = e; }
        else if (p < 200) { float e = sce[idx[tt][1] * 100 + (p - 100)]; lv = rv = e; }
        else if (p < 300) { int q = p - 200;
                            lv = be[idx[tt][2] * 100 + q];
                            rv = be[idx[tt][3] * 100 + q]; }
        else              { int q = p - 300;
                            lv = sbe[idx[tt][4] * 100 + q];
                            rv = sbe[idx[tt][5] * 100 + q]; }
        vec[tt][0][p] = lv;
        vec[tt][1][p] = rv;
    }
    __syncthreads();

    if (tid < 400) {
        int side = tid / 200, j = tid % 200;
        float acc[16];
        #pragma unroll
        for (int t = 0; t < 16; t++) acc[t] = 0.0f;

        for (int k4 = 0; k4 < D_IN / 4; k4++) {
            float w0 = Wt[(4 * k4 + 0) * D_RNN + j];
            float w1 = Wt[(4 * k4 + 1) * D_RNN + j];
            float w2 = Wt[(4 * k4 + 2) * D_RNN + j];
            float w3 = Wt[(4 * k4 + 3) * D_RNN + j];
            #pragma unroll
            for (int t = 0; t < 16; t++) {
                float4 xv = *(const float4*)&vec[t][side][4 * k4];
                acc[t] += xv.x * w0 + xv.y * w1 + xv.z * w2 + xv.w * w3;
            }
        }
        float bias = blin[j];
        #pragma unroll
        for (int t = 0; t < 16; t++) {
            int g = g0 + t;
            int b = g >> 8, s = g & 255;
            xout[((side * BB + b) * SS + s) * D_RNN + j] = tanh_f(acc[t] + bias);
        }
    }
}

// ---------------- K2: gate-x GEMM via f16 dot2 ----------------
__launch_bounds__(512)
__global__ void k_gatex(const float* __restrict__ x, const unsigned* __restrict__ Wt16,
                        const float* __restrict__ bihl, const float* __restrict__ bhhl,
                        const float* __restrict__ bihr, const float* __restrict__ bhhr,
                        float* __restrict__ gx) {
    __shared__ __align__(16) unsigned xT16[100][40];
    int tid = threadIdx.x;
    int id = blockIdx.x;
    int dir = id >> 9;
    int rem = id & 511;
    int b = rem >> 3;
    int s0 = (rem & 7) * 32;

    const float2* xb2 = reinterpret_cast<const float2*>(
        x + ((dir * BB + b) * SS + s0) * D_RNN);
    for (int v = tid; v < 32 * 100; v += 512) {
        int tok = v / 100, kk = v % 100;
        float2 p = xb2[tok * 100 + kk];
        xT16[kk][tok] = packf16(p.x, p.y);
    }
    __syncthreads();

    const unsigned* Wp = Wt16 + dir * 100 * G4;
    int j0 = tid, j1 = tid + 512;
    float acc0[32], acc1[32];
    #pragma unroll
    for (int t = 0; t < 32; t++) { acc0[t] = 0.0f; acc1[t] = 0.0f; }

    for (int kk = 0; kk < 100; kk++) {
        unsigned w0 = Wp[kk * G4 + j0];
        unsigned w1 = Wp[kk * G4 + j1];
        #pragma unroll
        for (int m = 0; m < 8; m++) {
            uint4 xx = *(const uint4*)&xT16[kk][4 * m];
            acc0[4 * m + 0] = dot2acc(xx.x, w0, acc0[4 * m + 0]);
            acc0[4 * m + 1] = dot2acc(xx.y, w0, acc0[4 * m + 1]);
            acc0[4 * m + 2] = dot2acc(xx.z, w0, acc0[4 * m + 2]);
            acc0[4 * m + 3] = dot2acc(xx.w, w0, acc0[4 * m + 3]);
            acc1[4 * m + 0] = dot2acc(xx.x, w1, acc1[4 * m + 0]);
            acc1[4 * m + 1] = dot2acc(xx.y, w1, acc1[4 * m + 1]);
            acc1[4 * m + 2] = dot2acc(xx.z, w1, acc1[4 * m + 2]);
            acc1[4 * m + 3] = dot2acc(xx.w, w1, acc1[4 * m + 3]);
        }
    }

    float bs0, bs1;
    if (dir) { bs0 = bihr[j0] + bhhr[j0]; bs1 = bihr[j1] + bhhr[j1]; }
    else     { bs0 = bihl[j0] + bhhl[j0]; bs1 = bihl[j1] + bhhl[j1]; }

    float* gbase = gx + ((dir * BB + b) * SS + s0) * G4;
    #pragma unroll
    for (int t = 0; t < 32; t++) {
        gbase[t * G4 + j0] = acc0[t] + bs0;
        gbase[t * G4 + j1] = acc1[t] + bs1;
    }
}

// ---------------- K3: LSTM, ONE block per (dir,b). 256 thr, 1 wave/SIMD.
// Thread (rg=t>>2, ks=t&3) owns 16 gate rows {j*64+rg} over k in [ks*64,+64).
// 128 weight uint4/thread: i0-3 (64) AGPR, i4-5 + i6:j<4 (36) VGPR,
// i6:j>=4 + i7 (28) streamed from LDS in THREAD-ORDER layout (wave reads
// 1024 contiguous B => zero bank conflicts). h padded to 36 u32 per ks-slice
// (disjoint bank-quads). DPP quad reduce; thread t finalizes h-column t.
__global__ void
__attribute__((amdgpu_flat_work_group_size(256, 256), amdgpu_waves_per_eu(1, 1)))
k_lstm(const uint4* __restrict__ wp4, const float* __restrict__ gx,
       float* __restrict__ out) {
    __shared__ __align__(16) uint4 wls[28 * 256];     // 114688 B, [m][t] thread-order
    __shared__ __align__(16) float4 gates4[256];      // 4096 B, [col]={i,f,g,o}
    __shared__ __align__(16) unsigned hbuf[4 * 36];   // 576 B, padded ks-slices

    int t = threadIdx.x;
    int rg = t >> 2, ks = t & 3;
    int bid = blockIdx.x;
    int dir = bid >> 6, b = bid & 63;

    const uint4* wp = wp4 + (size_t)dir * 32768;

    // ---- one-time loads (all coalesced: idx = q*256 + t) ----
    uint4 wa[4][16];                 // i=0..3 -> AGPR (256)
    #pragma unroll
    for (int i = 0; i < 4; i++)
        #pragma unroll
        for (int j = 0; j < 16; j++)
            wa[i][j] = wp[((i * 16 + j) << 8) + t];
    #pragma unroll
    for (int i = 0; i < 4; i++)
        #pragma unroll
        for (int j = 0; j < 16; j++)
            asm volatile("" : "+a"(wa[i][j].x), "+a"(wa[i][j].y),
                              "+a"(wa[i][j].z), "+a"(wa[i][j].w));

    uint4 wv[2][16];                 // i=4..5 -> VGPR (128)
    #pragma unroll
    for (int i = 0; i < 2; i++)
        #pragma unroll
        for (int j = 0; j < 16; j++)
            wv[i][j] = wp[(((i + 4) * 16 + j) << 8) + t];
    uint4 wv6[4];                    // i=6, j=0..3 -> VGPR (16)
    #pragma unroll
    for (int j = 0; j < 4; j++)
        wv6[j] = wp[((96 + j) << 8) + t];
    #pragma unroll
    for (int i = 0; i < 2; i++)
        #pragma unroll
        for (int j = 0; j < 16; j++)
            asm volatile("" : "+v"(wv[i][j].x), "+v"(wv[i][j].y),
                              "+v"(wv[i][j].z), "+v"(wv[i][j].w));
    #pragma unroll
    for (int j = 0; j < 4; j++)
        asm volatile("" : "+v"(wv6[j].x), "+v"(wv6[j].y),
                          "+v"(wv6[j].z), "+v"(wv6[j].w));

    // streamed set -> LDS in thread order: m<12: (i=6, j=4+m); else (i=7, j=m-12)
    #pragma unroll
    for (int m = 0; m < 12; m++)
        wls[m * 256 + t] = wp[((100 + m) << 8) + t];
    #pragma unroll
    for (int m = 0; m < 16; m++)
        wls[(12 + m) * 256 + t] = wp[((112 + m) << 8) + t];

    if (t < 144) hbuf[t] = 0u;

    const float* gxp = gx + (size_t)(dir * BB + b) * SS * G4;
    float* outp = out + (size_t)b * SS * (2 * HID) + dir * HID + t;
    float cst = 0.0f;
    int ts = dir ? (SS - 1) : 0;
    int dstep = dir ? -1 : 1;
    float gxc[4];
    #pragma unroll
    for (int g = 0; g < 4; g++) gxc[g] = gxp[(size_t)ts * G4 + g * 256 + t];
    __syncthreads();

    int hbase = ks * 36;                 // padded u32 base of own h slice
    int hwidx = (t >> 6) * 72 + (t & 63);  // u16 write index for h-col t
    unsigned short* hs = reinterpret_cast<unsigned short*>(hbuf);

    for (int s = 0; s < SS; s++) {
        float acc[16];
        #pragma unroll
        for (int j = 0; j < 16; j++) acc[j] = 0.0f;

#define DOT4(A, H, W4) \
        A = dot2acc((H).x, (W4).x, A); A = dot2acc((H).y, (W4).y, A); \
        A = dot2acc((H).z, (W4).z, A); A = dot2acc((H).w, (W4).w, A);

        // register chunks, h loaded per-i (narrow liveness)
        #pragma unroll
        for (int i = 0; i < 4; i++) {
            uint4 hi = *(const uint4*)&hbuf[hbase + 4 * i];
            #pragma unroll
            for (int j = 0; j < 16; j++) { DOT4(acc[j], hi, wa[i][j]); }
        }
        #pragma unroll
        for (int i = 0; i < 2; i++) {
            uint4 hi = *(const uint4*)&hbuf[hbase + 16 + 4 * i];
            #pragma unroll
            for (int j = 0; j < 16; j++) { DOT4(acc[j], hi, wv[i][j]); }
        }
        {
            uint4 h6 = *(const uint4*)&hbuf[hbase + 24];
            #pragma unroll
            for (int j = 0; j < 4; j++) { DOT4(acc[j], h6, wv6[j]); }
            // streamed i=6, j=4..15 (batches of 4 to bound liveness)
            #pragma unroll
            for (int m = 0; m < 12; m += 4) {
                uint4 a0 = wls[(m + 0) * 256 + t];
                uint4 a1 = wls[(m + 1) * 256 + t];
                uint4 a2 = wls[(m + 2) * 256 + t];
                uint4 a3 = wls[(m + 3) * 256 + t];
                DOT4(acc[4 + m], h6, a0);
                DOT4(acc[5 + m], h6, a1);
                DOT4(acc[6 + m], h6, a2);
                DOT4(acc[7 + m], h6, a3);
            }
            uint4 h7 = *(const uint4*)&hbuf[hbase + 28];
            #pragma unroll
            for (int m = 0; m < 16; m += 4) {
                uint4 a0 = wls[(12 + m + 0) * 256 + t];
                uint4 a1 = wls[(12 + m + 1) * 256 + t];
                uint4 a2 = wls[(12 + m + 2) * 256 + t];
                uint4 a3 = wls[(12 + m + 3) * 256 + t];
                DOT4(acc[m + 0], h7, a0);
                DOT4(acc[m + 1], h7, a1);
                DOT4(acc[m + 2], h7, a2);
                DOT4(acc[m + 3], h7, a3);
            }
        }
#undef DOT4

        // ---- cross-ks reduction (DPP quad butterfly) ----
        #pragma unroll
        for (int j = 0; j < 16; j++) acc[j] = quad_sum(acc[j]);

        if (ks == 0) {
            #pragma unroll
            for (int jc = 0; jc < 4; jc++)
                gates4[jc * 64 + rg] =
                    make_float4(acc[jc], acc[4 + jc], acc[8 + jc], acc[12 + jc]);
        }
        __syncthreads();

        // ---- finalize column t ----
        {
            float4 gt = gates4[t];
            float ig = sigm_f(gt.x + gxc[0]);
            float fg = sigm_f(gt.y + gxc[1]);
            float gg = tanh_f(gt.z + gxc[2]);
            float og = sigm_f(gt.w + gxc[3]);
            cst = fg * cst + ig * gg;
            float hv = og * tanh_f(cst);
            outp[(size_t)ts * (2 * HID)] = hv;
            hs[hwidx] = __builtin_bit_cast(unsigned short, (_Float16)hv);
            // prefetch next step's gx (latency hidden by next dot phase)
            int tn = (s < SS - 1) ? (ts + dstep) : ts;
            #pragma unroll
            for (int g = 0; g < 4; g++) gxc[g] = gxp[(size_t)tn * G4 + g * 256 + t];
        }
        __syncthreads();

        ts += dstep;
    }
}

extern "C" void kernel_launch(void* const* d_in, const int* in_sizes, int n_in,
                              void* d_out, int out_size, void* d_ws, size_t ws_size,
                              hipStream_t stream) {
    const int* char_features      = (const int*)d_in[0];
    const int* bichar_left        = (const int*)d_in[1];
    const int* bichar_right       = (const int*)d_in[2];
    const int* static_char        = (const int*)d_in[3];
    const int* static_bichar_left = (const int*)d_in[4];
    const int* static_bichar_right= (const int*)d_in[5];
    const float* char_emb         = (const float*)d_in[6];
    const float* bichar_emb       = (const float*)d_in[7];
    const float* static_char_emb  = (const float*)d_in[8];
    const float* static_bichar_emb= (const float*)d_in[9];
    const float* W_lin            = (const float*)d_in[10];
    const float* b_lin            = (const float*)d_in[11];
    const float* Wih_l            = (const float*)d_in[12];
    const float* Whh_l            = (const float*)d_in[13];
    const float* bih_l            = (const float*)d_in[14];
    const float* bhh_l            = (const float*)d_in[15];
    const float* Wih_r            = (const float*)d_in[16];
    const float* Whh_r            = (const float*)d_in[17];
    const float* bih_r            = (const float*)d_in[18];
    const float* bhh_r            = (const float*)d_in[19];

    float* ws    = (float*)d_ws;
    float* wtlin = ws + OFF_WTLIN;
    unsigned* wtih16 = (unsigned*)(ws + OFF_WTIH);
    uint4* wp4   = (uint4*)(ws + OFF_WPACK);
    float* xbuf  = ws + OFF_X;
    float* gxbuf = ws + OFF_GX;
    float* out   = (float*)d_out;

    kt_wlin<<<(D_RNN * D_IN + 255) / 256, 256, 0, stream>>>(W_lin, wtlin);
    kt_wih16<<<(2 * G4 * 100 + 255) / 256, 256, 0, stream>>>(Wih_l, Wih_r, wtih16);
    kt_wpack4<<<(2 * 8 * 16 * 256) / 256, 256, 0, stream>>>(Whh_l, Whh_r, wp4);

    k_embed_linear<<<(BB * SS) / 16, 512, 0, stream>>>(
        char_features, bichar_left, bichar_right, static_char,
        static_bichar_left, static_bichar_right,
        char_emb, bichar_emb, static_char_emb, static_bichar_emb,
        wtlin, b_lin, xbuf);

    k_gatex<<<(2 * BB * SS) / 32, 512, 0, stream>>>(
        xbuf, wtih16, bih_l, bhh_l, bih_r, bhh_r, gxbuf);

    k_lstm<<<2 * BB, 256, 0, stream>>>(wp4, gxbuf, out);
}